// Round 4
// baseline (567.947 us; speedup 1.0000x reference)
//
#include <hip/hip_runtime.h>
#include <math.h>

#define N 8192
#define D 1024
#define INV_T 14.285714285714286f   // 1/0.07; also the fixed LSE max (|cos|<=1)

typedef unsigned short ushortT;
typedef unsigned int uintT;
typedef __bf16 bf16x8 __attribute__((ext_vector_type(8)));
typedef float f32x4 __attribute__((ext_vector_type(4)));

#define AS1 __attribute__((address_space(1)))
#define AS3 __attribute__((address_space(3)))

__device__ __forceinline__ ushortT f2bf(float x) {
    uintT u = __float_as_uint(x);
    return (ushortT)((u + 0x7fffu + ((u >> 16) & 1u)) >> 16);   // RNE
}
__device__ __forceinline__ float bf2f(ushortT h) {
    return __uint_as_float(((uintT)h) << 16);
}

// ===========================================================================
// Kernel 1: per-row L2-normalize q,k; write bf16 hi/lo splits; diag logits.
// ===========================================================================
__global__ __launch_bounds__(256)
void normalize_split_kernel(const float* __restrict__ q, const float* __restrict__ k,
                            ushortT* __restrict__ qs, ushortT* __restrict__ ks,
                            float* __restrict__ diag) {
    const int row = blockIdx.x;
    const int tid = threadIdx.x;
    const float4 a = *(const float4*)(q + (size_t)row * D + tid * 4);
    const float4 b = *(const float4*)(k + (size_t)row * D + tid * 4);
    float sqq = a.x*a.x + a.y*a.y + a.z*a.z + a.w*a.w;
    float skk = b.x*b.x + b.y*b.y + b.z*b.z + b.w*b.w;
    float sqk = a.x*b.x + a.y*b.y + a.z*b.z + a.w*b.w;
    #pragma unroll
    for (int m = 1; m < 64; m <<= 1) {
        sqq += __shfl_xor(sqq, m, 64);
        skk += __shfl_xor(skk, m, 64);
        sqk += __shfl_xor(sqk, m, 64);
    }
    __shared__ float red[3][4];
    __shared__ float s_iq, s_ik;
    const int wid = tid >> 6, lane = tid & 63;
    if (lane == 0) { red[0][wid] = sqq; red[1][wid] = skk; red[2][wid] = sqk; }
    __syncthreads();
    if (tid == 0) {
        float s0 = red[0][0] + red[0][1] + red[0][2] + red[0][3];
        float s1 = red[1][0] + red[1][1] + red[1][2] + red[1][3];
        float s2 = red[2][0] + red[2][1] + red[2][2] + red[2][3];
        float iq = 1.0f / fmaxf(sqrtf(s0), 1e-12f);
        float ik = 1.0f / fmaxf(sqrtf(s1), 1e-12f);
        s_iq = iq; s_ik = ik;
        diag[row] = s2 * iq * ik * INV_T;
    }
    __syncthreads();
    const float iq = s_iq, ik = s_ik;

    const size_t base = (size_t)row * D + tid * 4;
    const size_t LO = (size_t)N * D;
    float av[4] = {a.x * iq, a.y * iq, a.z * iq, a.w * iq};
    float bv[4] = {b.x * ik, b.y * ik, b.z * ik, b.w * ik};
    ushort4 qh, ql, kh, kl;
    ushortT* qhp = (ushortT*)&qh; ushortT* qlp = (ushortT*)&ql;
    ushortT* khp = (ushortT*)&kh; ushortT* klp = (ushortT*)&kl;
    #pragma unroll
    for (int j = 0; j < 4; ++j) {
        ushortT h = f2bf(av[j]); qhp[j] = h; qlp[j] = f2bf(av[j] - bf2f(h));
        ushortT g = f2bf(bv[j]); khp[j] = g; klp[j] = f2bf(bv[j] - bf2f(g));
    }
    *(ushort4*)(qs + base)      = qh;
    *(ushort4*)(qs + LO + base) = ql;
    *(ushort4*)(ks + base)      = kh;
    *(ushort4*)(ks + LO + base) = kl;
}

// ===========================================================================
// Kernel 2: 256x256-tile 8-phase MFMA GEMM over virtual K'=3072
// (A'=[Ah|Ah|Al], B'=[Bh|Bl|Bh] -> Ah.Bh + Ah.Bl + Al.Bh), fused
// exp((cos-1)/T) + row/col sums. 512 thr = 8 waves (2Mx4N), BK=64 in two
// K-halves of 32. LDS 128 KiB double-buffered; raw s_barrier, counted
// vmcnt(4), setprio around MFMA clusters. Swizzle slot^=(r&3)^((r>>2)&3)
// applied on pre-swizzled global source AND ds_read (involution).
// ===========================================================================
#define NT 48            // 3072 / 64
#define LDSBUF 65536     // bytes per K-tile buffer: A 32K + B 32K

__global__ __launch_bounds__(512, 2)
void mfma8_lse_kernel(const ushortT* __restrict__ qs, const ushortT* __restrict__ ks,
                      float* __restrict__ rowsum, float* __restrict__ colsum) {
    __shared__ __align__(16) char lds[2 * LDSBUF];

    // XCD-chunked bijective swizzle: 1024 wgs, 8 XCDs, 128 per XCD
    const int wg  = blockIdx.x;
    const int swzb = (wg & 7) * 128 + (wg >> 3);
    const int bi  = swzb >> 5;
    const int bj  = swzb & 31;

    const int tid  = threadIdx.x;
    const int w    = tid >> 6;
    const int lane = tid & 63;
    const int wm   = w >> 2, wn = w & 3;       // wave grid 2M x 4N
    const int la   = lane & 15, lq = lane >> 4;

    // ---- staging thread-invariants (pre-swizzled global source) ----
    // linear 16B pos within 8KB chunk: r_loc = tid>>2 (row), s_phys = tid&3
    const int s_log = (tid & 3) ^ ((tid >> 2) & 3) ^ ((tid >> 4) & 3);
    const size_t LO = (size_t)N * D;
    const int r_loc = tid >> 2;
    const size_t arow0 = (size_t)(bi * 256 +       r_loc) * D + s_log * 8;
    const size_t arow1 = (size_t)(bi * 256 + 128 + r_loc) * D + s_log * 8;
    const size_t brow0 = (size_t)(bj * 256 +       r_loc) * D + s_log * 8;
    const size_t brow1 = (size_t)(bj * 256 + 128 + r_loc) * D + s_log * 8;

    // ---- fragment-read swizzle (byte offset), same for all frags ----
    const int sw = ((lq ^ (la & 3) ^ ((la >> 2) & 3)) * 16);

    f32x4 acc[8][4] = {};

    // STAGE one half (256 rows x 32 cols of A or B) = 2 global_load_lds calls
#define STAGE(tsrc, dp, kk, ISB) { \
    const int sg_ = (tsrc) >> 4; \
    const size_t pl_ = (ISB) ? ((sg_ == 1) ? LO : 0) : ((sg_ == 2) ? LO : 0); \
    const ushortT* sp_ = ((ISB) ? ks : qs) + pl_ + (size_t)(((tsrc) & 15) * 64 + (kk) * 32); \
    char* dst_ = lds + (dp) * LDSBUF + ((ISB) ? 32768 : 0) + (kk) * 16384 + w * 1024; \
    __builtin_amdgcn_global_load_lds((const AS1 void*)(sp_ + ((ISB) ? brow0 : arow0)), \
                                     (AS3 void*)dst_, 16, 0, 0); \
    __builtin_amdgcn_global_load_lds((const AS1 void*)(sp_ + ((ISB) ? brow1 : arow1)), \
                                     (AS3 void*)(dst_ + 8192), 16, 0, 0); }

#define RD_A(mh, kk) { const char* ab_ = bufb + (kk) * 16384; \
    aF[0] = *(const bf16x8*)(ab_ + (wm * 128 + (mh) * 64 +  0 + la) * 64 + sw); \
    aF[1] = *(const bf16x8*)(ab_ + (wm * 128 + (mh) * 64 + 16 + la) * 64 + sw); \
    aF[2] = *(const bf16x8*)(ab_ + (wm * 128 + (mh) * 64 + 32 + la) * 64 + sw); \
    aF[3] = *(const bf16x8*)(ab_ + (wm * 128 + (mh) * 64 + 48 + la) * 64 + sw); }

#define RD_B(kk) { const char* bb_ = bufb + 32768 + (kk) * 16384; \
    bF[0] = *(const bf16x8*)(bb_ + (wn * 64 +  0 + la) * 64 + sw); \
    bF[1] = *(const bf16x8*)(bb_ + (wn * 64 + 16 + la) * 64 + sw); \
    bF[2] = *(const bf16x8*)(bb_ + (wn * 64 + 32 + la) * 64 + sw); \
    bF[3] = *(const bf16x8*)(bb_ + (wn * 64 + 48 + la) * 64 + sw); }

#define MM(mh) { \
    _Pragma("unroll") for (int m_ = 0; m_ < 4; ++m_) \
    _Pragma("unroll") for (int n_ = 0; n_ < 4; ++n_) \
        acc[(mh) * 4 + m_][n_] = __builtin_amdgcn_mfma_f32_16x16x32_bf16( \
            aF[m_], bF[n_], acc[(mh) * 4 + m_][n_], 0, 0, 0); }

#define BAR()  __builtin_amdgcn_s_barrier()
#define LGKM0() asm volatile("s_waitcnt lgkmcnt(0)" ::: "memory")
#define VM4()  asm volatile("s_waitcnt vmcnt(4)" ::: "memory")

    // ---- prologue: stage tile 0 into buf0: order hA0,hB0,hA1,hB1 ----
    STAGE(0, 0, 0, 0);
    STAGE(0, 0, 0, 1);
    STAGE(0, 0, 1, 0);
    STAGE(0, 0, 1, 1);
    VM4();                      // hA0,hB0 of tile 0 landed (all waves pre-barrier)
    BAR();

    for (int t = 0; t < NT; ++t) {
        const int tn = (t + 1 < NT) ? (t + 1) : (NT - 1);  // source clamp
        const int dp = (t + 1) & 1;                        // dest parity UNclamped
        const char* bufb = lds + (t & 1) * LDSBUF;
        bf16x8 aF[4], bF[4];

        // P1: quadrant (mh0, kk0); stage t+1.hA0
        RD_A(0, 0); RD_B(0);
        STAGE(tn, dp, 0, 0);
        BAR(); LGKM0();
        __builtin_amdgcn_s_setprio(1); MM(0); __builtin_amdgcn_s_setprio(0);
        BAR();

        // P2: (mh1, kk0), B regs reused; stage t+1.hB0; vmcnt(4) -> t.hA1,t.hB1
        RD_A(1, 0);
        STAGE(tn, dp, 0, 1);
        VM4();
        BAR(); LGKM0();
        __builtin_amdgcn_s_setprio(1); MM(1); __builtin_amdgcn_s_setprio(0);
        BAR();

        // P3: (mh0, kk1); stage t+1.hA1
        RD_A(0, 1); RD_B(1);
        STAGE(tn, dp, 1, 0);
        BAR(); LGKM0();
        __builtin_amdgcn_s_setprio(1); MM(0); __builtin_amdgcn_s_setprio(0);
        BAR();

        // P4: (mh1, kk1); stage t+1.hB1; vmcnt(4) -> t+1.hA0,hB0
        RD_A(1, 1);
        STAGE(tn, dp, 1, 1);
        VM4();
        BAR(); LGKM0();
        __builtin_amdgcn_s_setprio(1); MM(1); __builtin_amdgcn_s_setprio(0);
        BAR();
    }

    // ---- epilogue: exp((cos-1)/T), row/col partial sums, atomics ----
    #pragma unroll
    for (int M = 0; M < 8; ++M)
        #pragma unroll
        for (int n = 0; n < 4; ++n)
            #pragma unroll
            for (int r = 0; r < 4; ++r)
                acc[M][n][r] = __expf((acc[M][n][r] - 1.0f) * INV_T);

    // rows: global row = bi*256 + wm*128 + M*16 + lq*4 + r; reduce over la
    #pragma unroll
    for (int M = 0; M < 8; ++M)
        #pragma unroll
        for (int r = 0; r < 4; ++r) {
            float v = acc[M][0][r] + acc[M][1][r] + acc[M][2][r] + acc[M][3][r];
            v += __shfl_xor(v, 1, 64);
            v += __shfl_xor(v, 2, 64);
            v += __shfl_xor(v, 4, 64);
            v += __shfl_xor(v, 8, 64);
            if (la == 0)
                atomicAdd(&rowsum[bi * 256 + wm * 128 + M * 16 + lq * 4 + r], v);
        }

    // cols: global col = bj*256 + wn*64 + n*16 + la; reduce over lq
    #pragma unroll
    for (int n = 0; n < 4; ++n) {
        float v = 0.f;
        #pragma unroll
        for (int M = 0; M < 8; ++M)
            #pragma unroll
            for (int r = 0; r < 4; ++r)
                v += acc[M][n][r];
        v += __shfl_xor(v, 16, 64);
        v += __shfl_xor(v, 32, 64);
        if (lq == 0)
            atomicAdd(&colsum[bj * 256 + wn * 64 + n * 16 + la], v);
    }
#undef STAGE
#undef RD_A
#undef RD_B
#undef MM
#undef BAR
#undef LGKM0
#undef VM4
}

// ===========================================================================
// Kernel 3: loss = M + ( 0.5*sum(log rs + log cs) - sum(diag) ) / N
// ===========================================================================
__global__ __launch_bounds__(1024)
void final_kernel(const float* __restrict__ rowsum, const float* __restrict__ colsum,
                  const float* __restrict__ diag, float* __restrict__ out) {
    const int tid = threadIdx.x;
    float p = 0.f;
    for (int i = tid; i < N; i += 1024)
        p += 0.5f * (logf(rowsum[i]) + logf(colsum[i])) - diag[i];
    #pragma unroll
    for (int m = 1; m < 64; m <<= 1) p += __shfl_xor(p, m, 64);
    __shared__ float red[16];
    const int wid = tid >> 6, lane = tid & 63;
    if (lane == 0) red[wid] = p;
    __syncthreads();
    if (tid == 0) {
        float t = 0.f;
        #pragma unroll
        for (int w = 0; w < 16; ++w) t += red[w];
        out[0] = INV_T + t / (float)N;
    }
}

// ===========================================================================
// FALLBACK PATH (fp32 VALU GEMM, needs only 5*N floats of ws)
// ===========================================================================
#define BT 128
__global__ __launch_bounds__(256)
void norms_diag_kernel(const float* __restrict__ q, const float* __restrict__ k,
                       float* __restrict__ invq, float* __restrict__ invk,
                       float* __restrict__ diag) {
    const int row = blockIdx.x;
    const int tid = threadIdx.x;
    float4 a = *(const float4*)(q + (size_t)row * D + tid * 4);
    float4 b = *(const float4*)(k + (size_t)row * D + tid * 4);
    float sqq = a.x*a.x + a.y*a.y + a.z*a.z + a.w*a.w;
    float skk = b.x*b.x + b.y*b.y + b.z*b.z + b.w*b.w;
    float sqk = a.x*b.x + a.y*b.y + a.z*b.z + a.w*b.w;
    #pragma unroll
    for (int m = 1; m < 64; m <<= 1) {
        sqq += __shfl_xor(sqq, m, 64);
        skk += __shfl_xor(skk, m, 64);
        sqk += __shfl_xor(sqk, m, 64);
    }
    __shared__ float red[3][4];
    const int wid = tid >> 6, lane = tid & 63;
    if (lane == 0) { red[0][wid] = sqq; red[1][wid] = skk; red[2][wid] = sqk; }
    __syncthreads();
    if (tid == 0) {
        float s0 = red[0][0] + red[0][1] + red[0][2] + red[0][3];
        float s1 = red[1][0] + red[1][1] + red[1][2] + red[1][3];
        float s2 = red[2][0] + red[2][1] + red[2][2] + red[2][3];
        float iq = 1.0f / fmaxf(sqrtf(s0), 1e-12f);
        float ik = 1.0f / fmaxf(sqrtf(s1), 1e-12f);
        invq[row] = iq; invk[row] = ik;
        diag[row] = s2 * iq * ik * INV_T;
    }
}

#define KBF 16
#define LDTF 132
__global__ __launch_bounds__(256)
void gemm_lse_kernel(const float* __restrict__ q, const float* __restrict__ k,
                     const float* __restrict__ invq, const float* __restrict__ invk,
                     float* __restrict__ rowsum, float* __restrict__ colsum) {
    __shared__ float As[KBF * LDTF];
    __shared__ float Bs[KBF * LDTF];
    const int tid = threadIdx.x;
    const int tx = tid & 15;
    const int ty = tid >> 4;
    const int bi = blockIdx.y;
    const int bj = blockIdx.x;
    const float* qb = q + (size_t)(bi * BT) * D;
    const float* kb = k + (size_t)(bj * BT) * D;
    float acc[8][8] = {};
    for (int k0 = 0; k0 < D; k0 += KBF) {
        #pragma unroll
        for (int i = 0; i < 2; ++i) {
            int idx  = tid + i * 256;
            int row  = idx >> 2;
            int kc4  = idx & 3;
            float4 av = *(const float4*)(qb + (size_t)row * D + k0 + kc4 * 4);
            float4 bv = *(const float4*)(kb + (size_t)row * D + k0 + kc4 * 4);
            int base = (kc4 * 4) * LDTF + row;
            As[base] = av.x; As[base + LDTF] = av.y; As[base + 2*LDTF] = av.z; As[base + 3*LDTF] = av.w;
            Bs[base] = bv.x; Bs[base + LDTF] = bv.y; Bs[base + 2*LDTF] = bv.z; Bs[base + 3*LDTF] = bv.w;
        }
        __syncthreads();
        #pragma unroll
        for (int kk = 0; kk < KBF; ++kk) {
            const float* ap = &As[kk * LDTF + ty * 8];
            const float* bp = &Bs[kk * LDTF + tx * 8];
            float4 a0 = *(const float4*)(ap);
            float4 a1 = *(const float4*)(ap + 4);
            float4 b0 = *(const float4*)(bp);
            float4 b1 = *(const float4*)(bp + 4);
            float ar[8] = {a0.x, a0.y, a0.z, a0.w, a1.x, a1.y, a1.z, a1.w};
            float br[8] = {b0.x, b0.y, b0.z, b0.w, b1.x, b1.y, b1.z, b1.w};
            #pragma unroll
            for (int r = 0; r < 8; ++r)
                #pragma unroll
                for (int c = 0; c < 8; ++c)
                    acc[r][c] += ar[r] * br[c];
        }
        __syncthreads();
    }
    float iqr[8], ikc[8];
    #pragma unroll
    for (int r = 0; r < 8; ++r) iqr[r] = invq[bi * BT + ty * 8 + r] * INV_T;
    #pragma unroll
    for (int c = 0; c < 8; ++c) ikc[c] = invk[bj * BT + tx * 8 + c];
    float rowpart[8] = {};
    float colpart[8] = {};
    #pragma unroll
    for (int r = 0; r < 8; ++r)
        #pragma unroll
        for (int c = 0; c < 8; ++c) {
            float e = __expf(acc[r][c] * iqr[r] * ikc[c] - INV_T);
            rowpart[r] += e; colpart[c] += e;
        }
    #pragma unroll
    for (int r = 0; r < 8; ++r) {
        float v = rowpart[r];
        v += __shfl_xor(v, 1, 64); v += __shfl_xor(v, 2, 64);
        v += __shfl_xor(v, 4, 64); v += __shfl_xor(v, 8, 64);
        if (tx == 0) atomicAdd(&rowsum[bi * BT + ty * 8 + r], v);
    }
    __syncthreads();
    float* colbuf = As;
    #pragma unroll
    for (int c = 0; c < 8; ++c) colbuf[ty * 128 + tx * 8 + c] = colpart[c];
    __syncthreads();
    if (tid < 128) {
        float s = 0.f;
        #pragma unroll
        for (int t2 = 0; t2 < 16; ++t2) s += colbuf[t2 * 128 + tid];
        atomicAdd(&colsum[bj * BT + tid], s);
    }
}

// ===========================================================================
extern "C" void kernel_launch(void* const* d_in, const int* in_sizes, int n_in,
                              void* d_out, int out_size, void* d_ws, size_t ws_size,
                              hipStream_t stream) {
    const float* q = (const float*)d_in[0];
    const float* k = (const float*)d_in[1];

    const size_t splitBytes = 4ull * N * D * sizeof(ushortT);   // 64 MB
    const size_t needFast   = splitBytes + 3ull * N * sizeof(float);

    if (ws_size >= needFast) {
        ushortT* qs = (ushortT*)d_ws;                       // qh | ql
        ushortT* ks = qs + 2ull * N * D;                    // kh | kl
        float* tail  = (float*)((char*)d_ws + splitBytes);
        float* rowsum = tail;
        float* colsum = tail + N;
        float* diag   = tail + 2 * N;

        hipMemsetAsync(rowsum, 0, 2ull * N * sizeof(float), stream);
        normalize_split_kernel<<<N, 256, 0, stream>>>(q, k, qs, ks, diag);
        mfma8_lse_kernel<<<(N / 256) * (N / 256), 512, 0, stream>>>(qs, ks, rowsum, colsum);
        final_kernel<<<1, 1024, 0, stream>>>(rowsum, colsum, diag, (float*)d_out);
    } else {
        float* ws     = (float*)d_ws;
        float* invq   = ws;
        float* invk   = ws + N;
        float* rowsum = ws + 2 * N;
        float* colsum = ws + 3 * N;
        float* diag   = ws + 4 * N;
        hipMemsetAsync(rowsum, 0, 2ull * N * sizeof(float), stream);
        norms_diag_kernel<<<N, 256, 0, stream>>>(q, k, invq, invk, diag);
        gemm_lse_kernel<<<dim3(N / BT, N / BT), 256, 0, stream>>>(q, k, invq, invk, rowsum, colsum);
        final_kernel<<<1, 1024, 0, stream>>>(rowsum, colsum, diag, (float*)d_out);
    }
}

// Round 6
// 383.886 us; speedup vs baseline: 1.4795x; 1.4795x over previous
//
#include <hip/hip_runtime.h>
#include <math.h>

#define N 8192
#define D 1024
#define INV_T 14.285714285714286f   // 1/0.07; also the fixed LSE max (|cos|<=1)

typedef unsigned short ushortT;
typedef unsigned int uintT;
typedef __bf16 bf16x8 __attribute__((ext_vector_type(8)));
typedef float f32x4 __attribute__((ext_vector_type(4)));

#define AS1 __attribute__((address_space(1)))
#define AS3 __attribute__((address_space(3)))

__device__ __forceinline__ ushortT f2bf(float x) {
    uintT u = __float_as_uint(x);
    return (ushortT)((u + 0x7fffu + ((u >> 16) & 1u)) >> 16);   // RNE
}

// ===========================================================================
// Kernel 1: per-row L2-normalize q,k; write bf16 planes; diag logits (fp32).
// One block per row, 256 threads, each owns one float4 of q and k.
// ===========================================================================
__global__ __launch_bounds__(256)
void normalize_bf16_kernel(const float* __restrict__ q, const float* __restrict__ k,
                           ushortT* __restrict__ qh, ushortT* __restrict__ kh,
                           float* __restrict__ diag) {
    const int row = blockIdx.x;
    const int tid = threadIdx.x;
    const float4 a = *(const float4*)(q + (size_t)row * D + tid * 4);
    const float4 b = *(const float4*)(k + (size_t)row * D + tid * 4);
    float sqq = a.x*a.x + a.y*a.y + a.z*a.z + a.w*a.w;
    float skk = b.x*b.x + b.y*b.y + b.z*b.z + b.w*b.w;
    float sqk = a.x*b.x + a.y*b.y + a.z*b.z + a.w*b.w;
    #pragma unroll
    for (int m = 1; m < 64; m <<= 1) {
        sqq += __shfl_xor(sqq, m, 64);
        skk += __shfl_xor(skk, m, 64);
        sqk += __shfl_xor(sqk, m, 64);
    }
    __shared__ float red[3][4];
    __shared__ float s_iq, s_ik;
    const int wid = tid >> 6, lane = tid & 63;
    if (lane == 0) { red[0][wid] = sqq; red[1][wid] = skk; red[2][wid] = sqk; }
    __syncthreads();
    if (tid == 0) {
        float s0 = red[0][0] + red[0][1] + red[0][2] + red[0][3];
        float s1 = red[1][0] + red[1][1] + red[1][2] + red[1][3];
        float s2 = red[2][0] + red[2][1] + red[2][2] + red[2][3];
        float iq = 1.0f / fmaxf(sqrtf(s0), 1e-12f);
        float ik = 1.0f / fmaxf(sqrtf(s1), 1e-12f);
        s_iq = iq; s_ik = ik;
        diag[row] = s2 * iq * ik * INV_T;      // exact fp32 diagonal
    }
    __syncthreads();
    const float iq = s_iq, ik = s_ik;

    const size_t base = (size_t)row * D + tid * 4;
    float av[4] = {a.x * iq, a.y * iq, a.z * iq, a.w * iq};
    float bv[4] = {b.x * ik, b.y * ik, b.z * ik, b.w * ik};
    ushort4 qv, kv;
    ushortT* qp = (ushortT*)&qv; ushortT* kp = (ushortT*)&kv;
    #pragma unroll
    for (int j = 0; j < 4; ++j) { qp[j] = f2bf(av[j]); kp[j] = f2bf(bv[j]); }
    *(ushort4*)(qh + base) = qv;
    *(ushort4*)(kh + base) = kv;
}

// ===========================================================================
// Kernel 2: single-pass bf16 MFMA GEMM (qn . kn^T), fused exp + row/col sums.
// 128x128 tile, 4 waves (2x2), BK=64 (two K-halves of 32 per 128B LDS row).
// LDS rows: 8 x 16B slots, XOR-swizzled slot^=(r&7) via pre-swizzled
// global_load_lds source (proven zero-conflict in round 3).
// ===========================================================================
#define BT 128

__global__ __launch_bounds__(256)
void mfma_bf16_lse_kernel(const ushortT* __restrict__ qh, const ushortT* __restrict__ kh,
                          float* __restrict__ rowsum, float* __restrict__ colsum) {
    __shared__ __align__(16) char smemA[BT * 128];   // 16 KB: 128 rows x 64 bf16
    __shared__ __align__(16) char smemB[BT * 128];   // 16 KB

    // XCD-chunked swizzle: 4096 wgs, 8 XCDs, 512 per XCD
    const int wg  = blockIdx.x;
    const int swz = (wg & 7) * 512 + (wg >> 3);
    const int bi  = swz >> 6;
    const int bj  = swz & 63;

    const int tid  = threadIdx.x;
    const int w    = tid >> 6;
    const int lane = tid & 63;
    const int wr   = w >> 1, wc = w & 1;
    const int la   = lane & 15, lq = lane >> 4;

    // --- staging: pre-swizzled global element offsets (16B granules) ---
    // granule lin = i*256+tid -> LDS (row = lin>>3, phys slot = lin&7);
    // source column = (slot ^ (row&7)) * 8 within the BK=64 slab.
    size_t aoff[4], boff[4];
    #pragma unroll
    for (int i = 0; i < 4; ++i) {
        int lin = i * 256 + tid;
        int r   = lin >> 3;
        int s   = lin & 7;
        int sp  = s ^ (r & 7);
        aoff[i] = (size_t)(bi * BT + r) * D + sp * 8;
        boff[i] = (size_t)(bj * BT + r) * D + sp * 8;
    }

    // --- fragment LDS byte offsets (K-independent) ---
    // kk=0 logical slot = lq; kk=1 logical slot = lq^4; phys = logical^(row&7)
    int byteA0[4], byteA1[4], byteB0[4], byteB1[4];
    #pragma unroll
    for (int f = 0; f < 4; ++f) {
        int ra = wr * 64 + f * 16 + la;
        byteA0[f] = ra * 128 + ((lq       ^ (ra & 7)) * 16);
        byteA1[f] = ra * 128 + (((lq ^ 4) ^ (ra & 7)) * 16);
        int rb = wc * 64 + f * 16 + la;
        byteB0[f] = rb * 128 + ((lq       ^ (rb & 7)) * 16);
        byteB1[f] = rb * 128 + (((lq ^ 4) ^ (rb & 7)) * 16);
    }

    f32x4 acc[4][4] = {};

    for (int k0 = 0; k0 < D; k0 += 64) {
        #pragma unroll
        for (int i = 0; i < 4; ++i) {
            __builtin_amdgcn_global_load_lds(
                (const AS1 void*)(qh + aoff[i] + k0),
                (AS3 void*)(smemA + (i * 256 + w * 64) * 16), 16, 0, 0);
            __builtin_amdgcn_global_load_lds(
                (const AS1 void*)(kh + boff[i] + k0),
                (AS3 void*)(smemB + (i * 256 + w * 64) * 16), 16, 0, 0);
        }
        __syncthreads();

        bf16x8 a0[4], a1[4], b0[4], b1[4];
        #pragma unroll
        for (int f = 0; f < 4; ++f) {
            a0[f] = *(const bf16x8*)(smemA + byteA0[f]);
            a1[f] = *(const bf16x8*)(smemA + byteA1[f]);
            b0[f] = *(const bf16x8*)(smemB + byteB0[f]);
            b1[f] = *(const bf16x8*)(smemB + byteB1[f]);
        }
        #pragma unroll
        for (int m = 0; m < 4; ++m)
            #pragma unroll
            for (int n = 0; n < 4; ++n) {
                acc[m][n] = __builtin_amdgcn_mfma_f32_16x16x32_bf16(a0[m], b0[n], acc[m][n], 0, 0, 0);
                acc[m][n] = __builtin_amdgcn_mfma_f32_16x16x32_bf16(a1[m], b1[n], acc[m][n], 0, 0, 0);
            }
        __syncthreads();
    }

    // --- epilogue: e = exp((cos-1)/T); row/col partial sums; atomics ---
    #pragma unroll
    for (int m = 0; m < 4; ++m)
        #pragma unroll
        for (int n = 0; n < 4; ++n)
            #pragma unroll
            for (int r = 0; r < 4; ++r)
                acc[m][n][r] = __expf((acc[m][n][r] - 1.0f) * INV_T);

    // rows: D-row = lq*4 + reg (A side); cols spread over la. Reduce over la.
    #pragma unroll
    for (int m = 0; m < 4; ++m)
        #pragma unroll
        for (int r = 0; r < 4; ++r) {
            float v = acc[m][0][r] + acc[m][1][r] + acc[m][2][r] + acc[m][3][r];
            v += __shfl_xor(v, 1, 64);
            v += __shfl_xor(v, 2, 64);
            v += __shfl_xor(v, 4, 64);
            v += __shfl_xor(v, 8, 64);
            if (la == 0)
                atomicAdd(&rowsum[bi * BT + wr * 64 + m * 16 + lq * 4 + r], v);
        }

    // cols: D-col = la (B side); rows spread over lq. Reduce over lq.
    #pragma unroll
    for (int n = 0; n < 4; ++n) {
        float v = 0.f;
        #pragma unroll
        for (int m = 0; m < 4; ++m)
            #pragma unroll
            for (int r = 0; r < 4; ++r)
                v += acc[m][n][r];
        v += __shfl_xor(v, 16, 64);
        v += __shfl_xor(v, 32, 64);
        if (lq == 0)
            atomicAdd(&colsum[bj * BT + wc * 64 + n * 16 + la], v);
    }
}

// ===========================================================================
// Kernel 3: loss = M + ( 0.5*sum(log rs + log cs) - sum(diag) ) / N
// ===========================================================================
__global__ __launch_bounds__(1024)
void final_kernel(const float* __restrict__ rowsum, const float* __restrict__ colsum,
                  const float* __restrict__ diag, float* __restrict__ out) {
    const int tid = threadIdx.x;
    float p = 0.f;
    for (int i = tid; i < N; i += 1024)
        p += 0.5f * (logf(rowsum[i]) + logf(colsum[i])) - diag[i];
    #pragma unroll
    for (int m = 1; m < 64; m <<= 1) p += __shfl_xor(p, m, 64);
    __shared__ float red[16];
    const int wid = tid >> 6, lane = tid & 63;
    if (lane == 0) red[wid] = p;
    __syncthreads();
    if (tid == 0) {
        float t = 0.f;
        #pragma unroll
        for (int w = 0; w < 16; ++w) t += red[w];
        out[0] = INV_T + t / (float)N;
    }
}

// ===========================================================================
// FALLBACK PATH (fp32 VALU GEMM, needs only 5*N floats of ws)
// ===========================================================================
__global__ __launch_bounds__(256)
void norms_diag_kernel(const float* __restrict__ q, const float* __restrict__ k,
                       float* __restrict__ invq, float* __restrict__ invk,
                       float* __restrict__ diag) {
    const int row = blockIdx.x;
    const int tid = threadIdx.x;
    float4 a = *(const float4*)(q + (size_t)row * D + tid * 4);
    float4 b = *(const float4*)(k + (size_t)row * D + tid * 4);
    float sqq = a.x*a.x + a.y*a.y + a.z*a.z + a.w*a.w;
    float skk = b.x*b.x + b.y*b.y + b.z*b.z + b.w*b.w;
    float sqk = a.x*b.x + a.y*b.y + a.z*b.z + a.w*b.w;
    #pragma unroll
    for (int m = 1; m < 64; m <<= 1) {
        sqq += __shfl_xor(sqq, m, 64);
        skk += __shfl_xor(skk, m, 64);
        sqk += __shfl_xor(sqk, m, 64);
    }
    __shared__ float red[3][4];
    const int wid = tid >> 6, lane = tid & 63;
    if (lane == 0) { red[0][wid] = sqq; red[1][wid] = skk; red[2][wid] = sqk; }
    __syncthreads();
    if (tid == 0) {
        float s0 = red[0][0] + red[0][1] + red[0][2] + red[0][3];
        float s1 = red[1][0] + red[1][1] + red[1][2] + red[1][3];
        float s2 = red[2][0] + red[2][1] + red[2][2] + red[2][3];
        float iq = 1.0f / fmaxf(sqrtf(s0), 1e-12f);
        float ik = 1.0f / fmaxf(sqrtf(s1), 1e-12f);
        invq[row] = iq; invk[row] = ik;
        diag[row] = s2 * iq * ik * INV_T;
    }
}

#define KBF 16
#define LDTF 132
__global__ __launch_bounds__(256)
void gemm_lse_kernel(const float* __restrict__ q, const float* __restrict__ k,
                     const float* __restrict__ invq, const float* __restrict__ invk,
                     float* __restrict__ rowsum, float* __restrict__ colsum) {
    __shared__ float As[KBF * LDTF];
    __shared__ float Bs[KBF * LDTF];
    const int tid = threadIdx.x;
    const int tx = tid & 15;
    const int ty = tid >> 4;
    const int bi = blockIdx.y;
    const int bj = blockIdx.x;
    const float* qb = q + (size_t)(bi * BT) * D;
    const float* kb = k + (size_t)(bj * BT) * D;
    float acc[8][8] = {};
    for (int k0 = 0; k0 < D; k0 += KBF) {
        #pragma unroll
        for (int i = 0; i < 2; ++i) {
            int idx  = tid + i * 256;
            int row  = idx >> 2;
            int kc4  = idx & 3;
            float4 av = *(const float4*)(qb + (size_t)row * D + k0 + kc4 * 4);
            float4 bv = *(const float4*)(kb + (size_t)row * D + k0 + kc4 * 4);
            int base = (kc4 * 4) * LDTF + row;
            As[base] = av.x; As[base + LDTF] = av.y; As[base + 2*LDTF] = av.z; As[base + 3*LDTF] = av.w;
            Bs[base] = bv.x; Bs[base + LDTF] = bv.y; Bs[base + 2*LDTF] = bv.z; Bs[base + 3*LDTF] = bv.w;
        }
        __syncthreads();
        #pragma unroll
        for (int kk = 0; kk < KBF; ++kk) {
            const float* ap = &As[kk * LDTF + ty * 8];
            const float* bp = &Bs[kk * LDTF + tx * 8];
            float4 a0 = *(const float4*)(ap);
            float4 a1 = *(const float4*)(ap + 4);
            float4 b0 = *(const float4*)(bp);
            float4 b1 = *(const float4*)(bp + 4);
            float ar[8] = {a0.x, a0.y, a0.z, a0.w, a1.x, a1.y, a1.z, a1.w};
            float br[8] = {b0.x, b0.y, b0.z, b0.w, b1.x, b1.y, b1.z, b1.w};
            #pragma unroll
            for (int r = 0; r < 8; ++r)
                #pragma unroll
                for (int c = 0; c < 8; ++c)
                    acc[r][c] += ar[r] * br[c];
        }
        __syncthreads();
    }
    float iqr[8], ikc[8];
    #pragma unroll
    for (int r = 0; r < 8; ++r) iqr[r] = invq[bi * BT + ty * 8 + r] * INV_T;
    #pragma unroll
    for (int c = 0; c < 8; ++c) ikc[c] = invk[bj * BT + tx * 8 + c];
    float rowpart[8] = {};
    float colpart[8] = {};
    #pragma unroll
    for (int r = 0; r < 8; ++r)
        #pragma unroll
        for (int c = 0; c < 8; ++c) {
            float e = __expf(acc[r][c] * iqr[r] * ikc[c] - INV_T);
            rowpart[r] += e; colpart[c] += e;
        }
    #pragma unroll
    for (int r = 0; r < 8; ++r) {
        float v = rowpart[r];
        v += __shfl_xor(v, 1, 64); v += __shfl_xor(v, 2, 64);
        v += __shfl_xor(v, 4, 64); v += __shfl_xor(v, 8, 64);
        if (tx == 0) atomicAdd(&rowsum[bi * BT + ty * 8 + r], v);
    }
    __syncthreads();
    float* colbuf = As;
    #pragma unroll
    for (int c = 0; c < 8; ++c) colbuf[ty * 128 + tx * 8 + c] = colpart[c];
    __syncthreads();
    if (tid < 128) {
        float s = 0.f;
        #pragma unroll
        for (int t2 = 0; t2 < 16; ++t2) s += colbuf[t2 * 128 + tid];
        atomicAdd(&colsum[bj * BT + tid], s);
    }
}

// ===========================================================================
extern "C" void kernel_launch(void* const* d_in, const int* in_sizes, int n_in,
                              void* d_out, int out_size, void* d_ws, size_t ws_size,
                              hipStream_t stream) {
    const float* q = (const float*)d_in[0];
    const float* k = (const float*)d_in[1];

    const size_t planeBytes = 2ull * N * D * sizeof(ushortT);   // 32 MB (qh+kh)
    const size_t needFast   = planeBytes + 3ull * N * sizeof(float);

    if (ws_size >= needFast) {
        ushortT* qh = (ushortT*)d_ws;
        ushortT* kh = qh + (size_t)N * D;
        float* tail  = (float*)((char*)d_ws + planeBytes);
        float* rowsum = tail;
        float* colsum = tail + N;
        float* diag   = tail + 2 * N;

        hipMemsetAsync(rowsum, 0, 2ull * N * sizeof(float), stream);
        normalize_bf16_kernel<<<N, 256, 0, stream>>>(q, k, qh, kh, diag);
        mfma_bf16_lse_kernel<<<(N / BT) * (N / BT), 256, 0, stream>>>(qh, kh, rowsum, colsum);
        final_kernel<<<1, 1024, 0, stream>>>(rowsum, colsum, diag, (float*)d_out);
    } else {
        float* ws     = (float*)d_ws;
        float* invq   = ws;
        float* invk   = ws + N;
        float* rowsum = ws + 2 * N;
        float* colsum = ws + 3 * N;
        float* diag   = ws + 4 * N;
        hipMemsetAsync(rowsum, 0, 2ull * N * sizeof(float), stream);
        norms_diag_kernel<<<N, 256, 0, stream>>>(q, k, invq, invk, diag);
        gemm_lse_kernel<<<dim3(N / BT, N / BT), 256, 0, stream>>>(q, k, invq, invk, rowsum, colsum);
        final_kernel<<<1, 1024, 0, stream>>>(rowsum, colsum, diag, (float*)d_out);
    }
}

// Round 7
// 375.373 us; speedup vs baseline: 1.5130x; 1.0227x over previous
//
#include <hip/hip_runtime.h>
#include <math.h>

#define N 8192
#define D 1024
#define INV_T 14.285714285714286f   // 1/0.07; also the fixed LSE max (|cos|<=1)

typedef unsigned short ushortT;
typedef unsigned int uintT;
typedef __bf16 bf16x8 __attribute__((ext_vector_type(8)));
typedef float f32x4 __attribute__((ext_vector_type(4)));

#define AS1 __attribute__((address_space(1)))
#define AS3 __attribute__((address_space(3)))

__device__ __forceinline__ ushortT f2bf(float x) {
    uintT u = __float_as_uint(x);
    return (ushortT)((u + 0x7fffu + ((u >> 16) & 1u)) >> 16);   // RNE
}

// ===========================================================================
// Kernel 1: per-row L2-normalize q,k; write bf16 planes; diag logits (fp32).
// Also zero-inits rowsum/colsum and seeds out[0] = INV_T (replaces memset).
// ===========================================================================
__global__ __launch_bounds__(256)
void normalize_bf16_kernel(const float* __restrict__ q, const float* __restrict__ k,
                           ushortT* __restrict__ qh, ushortT* __restrict__ kh,
                           float* __restrict__ diag,
                           float* __restrict__ rowsum, float* __restrict__ colsum,
                           float* __restrict__ out) {
    const int row = blockIdx.x;
    const int tid = threadIdx.x;
    if (tid == 64) rowsum[row] = 0.f;
    if (tid == 65) colsum[row] = 0.f;
    if (row == 0 && tid == 66) out[0] = INV_T;

    const float4 a = *(const float4*)(q + (size_t)row * D + tid * 4);
    const float4 b = *(const float4*)(k + (size_t)row * D + tid * 4);
    float sqq = a.x*a.x + a.y*a.y + a.z*a.z + a.w*a.w;
    float skk = b.x*b.x + b.y*b.y + b.z*b.z + b.w*b.w;
    float sqk = a.x*b.x + a.y*b.y + a.z*b.z + a.w*b.w;
    #pragma unroll
    for (int m = 1; m < 64; m <<= 1) {
        sqq += __shfl_xor(sqq, m, 64);
        skk += __shfl_xor(skk, m, 64);
        sqk += __shfl_xor(sqk, m, 64);
    }
    __shared__ float red[3][4];
    __shared__ float s_iq, s_ik;
    const int wid = tid >> 6, lane = tid & 63;
    if (lane == 0) { red[0][wid] = sqq; red[1][wid] = skk; red[2][wid] = sqk; }
    __syncthreads();
    if (tid == 0) {
        float s0 = red[0][0] + red[0][1] + red[0][2] + red[0][3];
        float s1 = red[1][0] + red[1][1] + red[1][2] + red[1][3];
        float s2 = red[2][0] + red[2][1] + red[2][2] + red[2][3];
        float iq = 1.0f / fmaxf(sqrtf(s0), 1e-12f);
        float ik = 1.0f / fmaxf(sqrtf(s1), 1e-12f);
        s_iq = iq; s_ik = ik;
        diag[row] = s2 * iq * ik * INV_T;      // exact fp32 diagonal
    }
    __syncthreads();
    const float iq = s_iq, ik = s_ik;

    const size_t base = (size_t)row * D + tid * 4;
    float av[4] = {a.x * iq, a.y * iq, a.z * iq, a.w * iq};
    float bv[4] = {b.x * ik, b.y * ik, b.z * ik, b.w * ik};
    ushort4 qv, kv;
    ushortT* qp = (ushortT*)&qv; ushortT* kp = (ushortT*)&kv;
    #pragma unroll
    for (int j = 0; j < 4; ++j) { qp[j] = f2bf(av[j]); kp[j] = f2bf(bv[j]); }
    *(ushort4*)(qh + base) = qv;
    *(ushort4*)(kh + base) = kv;
}

// ===========================================================================
// Kernel 2: single-pass bf16 MFMA GEMM (qn . kn^T), fused exp + row/col sums.
// 128x128 tile, 4 waves (2x2), BK=64. NOW double-buffered (2x32KB LDS) with
// the minimal 2-phase schedule: issue STAGE(t+1) -> ds_read(t) -> MFMA(t) ->
// vmcnt(0) -> s_barrier. Zero-conflict slot^=(r&7) swizzle (proven r3/r6).
// ===========================================================================
#define BT 128

__global__ __launch_bounds__(256)
void mfma_bf16_lse_kernel(const ushortT* __restrict__ qh, const ushortT* __restrict__ kh,
                          float* __restrict__ rowsum, float* __restrict__ colsum) {
    __shared__ __align__(16) char lds[2 * 32768];   // [buf][A 16KB | B 16KB]

    // XCD-chunked swizzle: 4096 wgs, 8 XCDs, 512 per XCD
    const int wg  = blockIdx.x;
    const int swz = (wg & 7) * 512 + (wg >> 3);
    const int bi  = swz >> 6;
    const int bj  = swz & 63;

    const int tid  = threadIdx.x;
    const int w    = tid >> 6;
    const int lane = tid & 63;
    const int wr   = w >> 1, wc = w & 1;
    const int la   = lane & 15, lq = lane >> 4;

    // --- staging: pre-swizzled global element offsets (16B granules) ---
    size_t aoff[4], boff[4];
    #pragma unroll
    for (int i = 0; i < 4; ++i) {
        int lin = i * 256 + tid;
        int r   = lin >> 3;
        int s   = lin & 7;
        int sp  = s ^ (r & 7);
        aoff[i] = (size_t)(bi * BT + r) * D + sp * 8;
        boff[i] = (size_t)(bj * BT + r) * D + sp * 8;
    }

    // --- fragment LDS byte offsets (K-independent, relative to buf base) ---
    int byteA0[4], byteA1[4], byteB0[4], byteB1[4];
    #pragma unroll
    for (int f = 0; f < 4; ++f) {
        int ra = wr * 64 + f * 16 + la;
        byteA0[f] = ra * 128 + ((lq       ^ (ra & 7)) * 16);
        byteA1[f] = ra * 128 + (((lq ^ 4) ^ (ra & 7)) * 16);
        int rb = wc * 64 + f * 16 + la;
        byteB0[f] = rb * 128 + ((lq       ^ (rb & 7)) * 16);
        byteB1[f] = rb * 128 + (((lq ^ 4) ^ (rb & 7)) * 16);
    }

    f32x4 acc[4][4] = {};

#define STAGE(p, k0) do { \
    _Pragma("unroll") \
    for (int i_ = 0; i_ < 4; ++i_) { \
        __builtin_amdgcn_global_load_lds( \
            (const AS1 void*)(qh + aoff[i_] + (k0)), \
            (AS3 void*)(lds + (p) * 32768 + (i_ * 256 + w * 64) * 16), 16, 0, 0); \
        __builtin_amdgcn_global_load_lds( \
            (const AS1 void*)(kh + boff[i_] + (k0)), \
            (AS3 void*)(lds + (p) * 32768 + 16384 + (i_ * 256 + w * 64) * 16), 16, 0, 0); \
    } } while (0)

    // ---- prologue: stage tile 0 into buf 0 ----
    STAGE(0, 0);
    asm volatile("s_waitcnt vmcnt(0)" ::: "memory");
    __builtin_amdgcn_s_barrier();

    #pragma unroll 1
    for (int t = 0; t < 16; ++t) {
        const int cur = t & 1;
        const char* sA = lds + cur * 32768;
        const char* sB = sA + 16384;

        if (t < 15) { STAGE(cur ^ 1, (t + 1) * 64); }   // prefetch next tile

        bf16x8 a0[4], a1[4], b0[4], b1[4];
        #pragma unroll
        for (int f = 0; f < 4; ++f) {
            a0[f] = *(const bf16x8*)(sA + byteA0[f]);
            a1[f] = *(const bf16x8*)(sA + byteA1[f]);
            b0[f] = *(const bf16x8*)(sB + byteB0[f]);
            b1[f] = *(const bf16x8*)(sB + byteB1[f]);
        }
        #pragma unroll
        for (int m = 0; m < 4; ++m)
            #pragma unroll
            for (int n = 0; n < 4; ++n) {
                acc[m][n] = __builtin_amdgcn_mfma_f32_16x16x32_bf16(a0[m], b0[n], acc[m][n], 0, 0, 0);
                acc[m][n] = __builtin_amdgcn_mfma_f32_16x16x32_bf16(a1[m], b1[n], acc[m][n], 0, 0, 0);
            }

        asm volatile("s_waitcnt vmcnt(0)" ::: "memory");  // next tile landed
        __builtin_amdgcn_s_barrier();
    }
#undef STAGE

    // --- epilogue: e = exp((cos-1)/T); row/col partial sums; atomics ---
    #pragma unroll
    for (int m = 0; m < 4; ++m)
        #pragma unroll
        for (int n = 0; n < 4; ++n)
            #pragma unroll
            for (int r = 0; r < 4; ++r)
                acc[m][n][r] = __expf((acc[m][n][r] - 1.0f) * INV_T);

    // rows: D-row = lq*4 + reg (A side); cols spread over la. Reduce over la.
    #pragma unroll
    for (int m = 0; m < 4; ++m)
        #pragma unroll
        for (int r = 0; r < 4; ++r) {
            float v = acc[m][0][r] + acc[m][1][r] + acc[m][2][r] + acc[m][3][r];
            v += __shfl_xor(v, 1, 64);
            v += __shfl_xor(v, 2, 64);
            v += __shfl_xor(v, 4, 64);
            v += __shfl_xor(v, 8, 64);
            if (la == 0)
                atomicAdd(&rowsum[bi * BT + wr * 64 + m * 16 + lq * 4 + r], v);
        }

    // cols: D-col = la (B side); rows spread over lq. Reduce over lq.
    #pragma unroll
    for (int n = 0; n < 4; ++n) {
        float v = 0.f;
        #pragma unroll
        for (int m = 0; m < 4; ++m)
            #pragma unroll
            for (int r = 0; r < 4; ++r)
                v += acc[m][n][r];
        v += __shfl_xor(v, 16, 64);
        v += __shfl_xor(v, 32, 64);
        if (lq == 0)
            atomicAdd(&colsum[bj * BT + wc * 64 + n * 16 + la], v);
    }
}

// ===========================================================================
// Kernel 3: out += sum(0.5*(log rs + log cs) - diag)/N  (out pre-seeded INV_T)
// 8 blocks x 1024 threads, one atomicAdd per block.
// ===========================================================================
__global__ __launch_bounds__(1024)
void final_kernel(const float* __restrict__ rowsum, const float* __restrict__ colsum,
                  const float* __restrict__ diag, float* __restrict__ out) {
    const int tid = threadIdx.x;
    const int i = blockIdx.x * 1024 + tid;
    float p = 0.5f * (logf(rowsum[i]) + logf(colsum[i])) - diag[i];
    #pragma unroll
    for (int m = 1; m < 64; m <<= 1) p += __shfl_xor(p, m, 64);
    __shared__ float red[16];
    const int wid = tid >> 6, lane = tid & 63;
    if (lane == 0) red[wid] = p;
    __syncthreads();
    if (tid == 0) {
        float t = 0.f;
        #pragma unroll
        for (int w = 0; w < 16; ++w) t += red[w];
        atomicAdd(out, t / (float)N);
    }
}

// ===========================================================================
// FALLBACK PATH (fp32 VALU GEMM, needs only 5*N floats of ws)
// ===========================================================================
__global__ __launch_bounds__(256)
void norms_diag_kernel(const float* __restrict__ q, const float* __restrict__ k,
                       float* __restrict__ invq, float* __restrict__ invk,
                       float* __restrict__ diag, float* __restrict__ out) {
    const int row = blockIdx.x;
    const int tid = threadIdx.x;
    if (row == 0 && tid == 66) out[0] = INV_T;
    float4 a = *(const float4*)(q + (size_t)row * D + tid * 4);
    float4 b = *(const float4*)(k + (size_t)row * D + tid * 4);
    float sqq = a.x*a.x + a.y*a.y + a.z*a.z + a.w*a.w;
    float skk = b.x*b.x + b.y*b.y + b.z*b.z + b.w*b.w;
    float sqk = a.x*b.x + a.y*b.y + a.z*b.z + a.w*b.w;
    #pragma unroll
    for (int m = 1; m < 64; m <<= 1) {
        sqq += __shfl_xor(sqq, m, 64);
        skk += __shfl_xor(skk, m, 64);
        sqk += __shfl_xor(sqk, m, 64);
    }
    __shared__ float red[3][4];
    const int wid = tid >> 6, lane = tid & 63;
    if (lane == 0) { red[0][wid] = sqq; red[1][wid] = skk; red[2][wid] = sqk; }
    __syncthreads();
    if (tid == 0) {
        float s0 = red[0][0] + red[0][1] + red[0][2] + red[0][3];
        float s1 = red[1][0] + red[1][1] + red[1][2] + red[1][3];
        float s2 = red[2][0] + red[2][1] + red[2][2] + red[2][3];
        float iq = 1.0f / fmaxf(sqrtf(s0), 1e-12f);
        float ik = 1.0f / fmaxf(sqrtf(s1), 1e-12f);
        invq[row] = iq; invk[row] = ik;
        diag[row] = s2 * iq * ik * INV_T;
    }
}

#define KBF 16
#define LDTF 132
__global__ __launch_bounds__(256)
void gemm_lse_kernel(const float* __restrict__ q, const float* __restrict__ k,
                     const float* __restrict__ invq, const float* __restrict__ invk,
                     float* __restrict__ rowsum, float* __restrict__ colsum) {
    __shared__ float As[KBF * LDTF];
    __shared__ float Bs[KBF * LDTF];
    const int tid = threadIdx.x;
    const int tx = tid & 15;
    const int ty = tid >> 4;
    const int bi = blockIdx.y;
    const int bj = blockIdx.x;
    const float* qb = q + (size_t)(bi * BT) * D;
    const float* kb = k + (size_t)(bj * BT) * D;
    float acc[8][8] = {};
    for (int k0 = 0; k0 < D; k0 += KBF) {
        #pragma unroll
        for (int i = 0; i < 2; ++i) {
            int idx  = tid + i * 256;
            int row  = idx >> 2;
            int kc4  = idx & 3;
            float4 av = *(const float4*)(qb + (size_t)row * D + k0 + kc4 * 4);
            float4 bv = *(const float4*)(kb + (size_t)row * D + k0 + kc4 * 4);
            int base = (kc4 * 4) * LDTF + row;
            As[base] = av.x; As[base + LDTF] = av.y; As[base + 2*LDTF] = av.z; As[base + 3*LDTF] = av.w;
            Bs[base] = bv.x; Bs[base + LDTF] = bv.y; Bs[base + 2*LDTF] = bv.z; Bs[base + 3*LDTF] = bv.w;
        }
        __syncthreads();
        #pragma unroll
        for (int kk = 0; kk < KBF; ++kk) {
            const float* ap = &As[kk * LDTF + ty * 8];
            const float* bp = &Bs[kk * LDTF + tx * 8];
            float4 a0 = *(const float4*)(ap);
            float4 a1 = *(const float4*)(ap + 4);
            float4 b0 = *(const float4*)(bp);
            float4 b1 = *(const float4*)(bp + 4);
            float ar[8] = {a0.x, a0.y, a0.z, a0.w, a1.x, a1.y, a1.z, a1.w};
            float br[8] = {b0.x, b0.y, b0.z, b0.w, b1.x, b1.y, b1.z, b1.w};
            #pragma unroll
            for (int r = 0; r < 8; ++r)
                #pragma unroll
                for (int c = 0; c < 8; ++c)
                    acc[r][c] += ar[r] * br[c];
        }
        __syncthreads();
    }
    float iqr[8], ikc[8];
    #pragma unroll
    for (int r = 0; r < 8; ++r) iqr[r] = invq[bi * BT + ty * 8 + r] * INV_T;
    #pragma unroll
    for (int c = 0; c < 8; ++c) ikc[c] = invk[bj * BT + tx * 8 + c];
    float rowpart[8] = {};
    float colpart[8] = {};
    #pragma unroll
    for (int r = 0; r < 8; ++r)
        #pragma unroll
        for (int c = 0; c < 8; ++c) {
            float e = __expf(acc[r][c] * iqr[r] * ikc[c] - INV_T);
            rowpart[r] += e; colpart[c] += e;
        }
    #pragma unroll
    for (int r = 0; r < 8; ++r) {
        float v = rowpart[r];
        v += __shfl_xor(v, 1, 64); v += __shfl_xor(v, 2, 64);
        v += __shfl_xor(v, 4, 64); v += __shfl_xor(v, 8, 64);
        if (tx == 0) atomicAdd(&rowsum[bi * BT + ty * 8 + r], v);
    }
    __syncthreads();
    float* colbuf = As;
    #pragma unroll
    for (int c = 0; c < 8; ++c) colbuf[ty * 128 + tx * 8 + c] = colpart[c];
    __syncthreads();
    if (tid < 128) {
        float s = 0.f;
        #pragma unroll
        for (int t2 = 0; t2 < 16; ++t2) s += colbuf[t2 * 128 + tid];
        atomicAdd(&colsum[bj * BT + tid], s);
    }
}

// ===========================================================================
extern "C" void kernel_launch(void* const* d_in, const int* in_sizes, int n_in,
                              void* d_out, int out_size, void* d_ws, size_t ws_size,
                              hipStream_t stream) {
    const float* q = (const float*)d_in[0];
    const float* k = (const float*)d_in[1];

    const size_t planeBytes = 2ull * N * D * sizeof(ushortT);   // 32 MB (qh+kh)
    const size_t needFast   = planeBytes + 3ull * N * sizeof(float);

    if (ws_size >= needFast) {
        ushortT* qh = (ushortT*)d_ws;
        ushortT* kh = qh + (size_t)N * D;
        float* tail  = (float*)((char*)d_ws + planeBytes);
        float* rowsum = tail;
        float* colsum = tail + N;
        float* diag   = tail + 2 * N;

        normalize_bf16_kernel<<<N, 256, 0, stream>>>(q, k, qh, kh, diag,
                                                     rowsum, colsum, (float*)d_out);
        mfma_bf16_lse_kernel<<<(N / BT) * (N / BT), 256, 0, stream>>>(qh, kh, rowsum, colsum);
        final_kernel<<<N / 1024, 1024, 0, stream>>>(rowsum, colsum, diag, (float*)d_out);
    } else {
        float* ws     = (float*)d_ws;
        float* invq   = ws;
        float* invk   = ws + N;
        float* rowsum = ws + 2 * N;
        float* colsum = ws + 3 * N;
        float* diag   = ws + 4 * N;
        hipMemsetAsync(rowsum, 0, 2ull * N * sizeof(float), stream);
        norms_diag_kernel<<<N, 256, 0, stream>>>(q, k, invq, invk, diag, (float*)d_out);
        gemm_lse_kernel<<<dim3(N / BT, N / BT), 256, 0, stream>>>(q, k, invq, invk, rowsum, colsum);
        final_kernel<<<N / 1024, 1024, 0, stream>>>(rowsum, colsum, diag, (float*)d_out);
    }
}

// Round 9
// 296.685 us; speedup vs baseline: 1.9143x; 1.2652x over previous
//
#include <hip/hip_runtime.h>
#include <math.h>

#define N 8192
#define D 1024
#define INV_T 14.285714285714286f   // 1/0.07; also the fixed LSE max (|cos|<=1)

typedef unsigned short ushortT;
typedef unsigned int uintT;
typedef __bf16 bf16x8 __attribute__((ext_vector_type(8)));
typedef float f32x4 __attribute__((ext_vector_type(4)));

#define AS1 __attribute__((address_space(1)))
#define AS3 __attribute__((address_space(3)))

__device__ __forceinline__ ushortT f2bf(float x) {
    uintT u = __float_as_uint(x);
    return (ushortT)((u + 0x7fffu + ((u >> 16) & 1u)) >> 16);   // RNE
}

// ===========================================================================
// Kernel 1: per-row L2-normalize q,k; write bf16 planes; diag logits (fp32).
// Also zero-inits rowsum/colsum and seeds out[0] = INV_T (replaces memset).
// ===========================================================================
__global__ __launch_bounds__(256)
void normalize_bf16_kernel(const float* __restrict__ q, const float* __restrict__ k,
                           ushortT* __restrict__ qh, ushortT* __restrict__ kh,
                           float* __restrict__ diag,
                           float* __restrict__ rowsum, float* __restrict__ colsum,
                           float* __restrict__ out) {
    const int row = blockIdx.x;
    const int tid = threadIdx.x;
    if (tid == 64) rowsum[row] = 0.f;
    if (tid == 65) colsum[row] = 0.f;
    if (row == 0 && tid == 66) out[0] = INV_T;

    const float4 a = *(const float4*)(q + (size_t)row * D + tid * 4);
    const float4 b = *(const float4*)(k + (size_t)row * D + tid * 4);
    float sqq = a.x*a.x + a.y*a.y + a.z*a.z + a.w*a.w;
    float skk = b.x*b.x + b.y*b.y + b.z*b.z + b.w*b.w;
    float sqk = a.x*b.x + a.y*b.y + a.z*b.z + a.w*b.w;
    #pragma unroll
    for (int m = 1; m < 64; m <<= 1) {
        sqq += __shfl_xor(sqq, m, 64);
        skk += __shfl_xor(skk, m, 64);
        sqk += __shfl_xor(sqk, m, 64);
    }
    __shared__ float red[3][4];
    __shared__ float s_iq, s_ik;
    const int wid = tid >> 6, lane = tid & 63;
    if (lane == 0) { red[0][wid] = sqq; red[1][wid] = skk; red[2][wid] = sqk; }
    __syncthreads();
    if (tid == 0) {
        float s0 = red[0][0] + red[0][1] + red[0][2] + red[0][3];
        float s1 = red[1][0] + red[1][1] + red[1][2] + red[1][3];
        float s2 = red[2][0] + red[2][1] + red[2][2] + red[2][3];
        float iq = 1.0f / fmaxf(sqrtf(s0), 1e-12f);
        float ik = 1.0f / fmaxf(sqrtf(s1), 1e-12f);
        s_iq = iq; s_ik = ik;
        diag[row] = s2 * iq * ik * INV_T;      // exact fp32 diagonal
    }
    __syncthreads();
    const float iq = s_iq, ik = s_ik;

    const size_t base = (size_t)row * D + tid * 4;
    float av[4] = {a.x * iq, a.y * iq, a.z * iq, a.w * iq};
    float bv[4] = {b.x * ik, b.y * ik, b.z * ik, b.w * ik};
    ushort4 qv, kv;
    ushortT* qp = (ushortT*)&qv; ushortT* kp = (ushortT*)&kv;
    #pragma unroll
    for (int j = 0; j < 4; ++j) { qp[j] = f2bf(av[j]); kp[j] = f2bf(bv[j]); }
    *(ushort4*)(qh + base) = qv;
    *(ushort4*)(kh + base) = kv;
}

// ===========================================================================
// Kernel 2: 256x256-tile single-pass bf16 MFMA GEMM, fused exp + row/col sums.
// 8 waves (2M x 4N), wave-tile 128x64 (8x4 frags), BK=64, LDS 2x64KB dbuf.
// All staging for tile t+1 issued at tile t start (full-tile flight -> cheap
// drain). Two compute phases per tile (m0-3, m4-7), B regs live whole tile,
// setprio around MFMA clusters. Proven 128B-row slot^=(r&7) swizzle on both
// staging source and ds_read (2-way max = free).
// ===========================================================================
#define LBUF 65536
#define NT 16

__global__ __launch_bounds__(512, 2)
void mfma256_lse_kernel(const ushortT* __restrict__ qh, const ushortT* __restrict__ kh,
                        float* __restrict__ rowsum, float* __restrict__ colsum) {
    __shared__ __align__(16) char lds[2 * LBUF];   // [buf][A 32KB | B 32KB]

    // bijective XCD-chunked swizzle: 1024 wgs, 8 XCDs, 128 per XCD
    const int wg  = blockIdx.x;
    const int swz = (wg & 7) * 128 + (wg >> 3);
    const int bi  = swz >> 5;
    const int bj  = swz & 31;

    const int tid  = threadIdx.x;
    const int w    = tid >> 6;
    const int lane = tid & 63;
    const int wm   = w >> 2, wn = w & 3;       // wave grid 2M x 4N
    const int la   = lane & 15, lq = lane >> 4;

    // --- staging: pre-swizzled global element offsets (16B granules) ---
    // granule lin = i*512+tid -> LDS (row = lin>>3, phys slot = lin&7);
    // source k-chunk = (slot ^ (row&7)) * 8 within the BK=64 slab.
    size_t aoff[4], boff[4];
    int dstb[4];
    #pragma unroll
    for (int i = 0; i < 4; ++i) {
        int lin = i * 512 + tid;
        int r   = lin >> 3;
        int s   = lin & 7;
        int sp  = s ^ (r & 7);
        aoff[i] = (size_t)(bi * 256 + r) * D + sp * 8;
        boff[i] = (size_t)(bj * 256 + r) * D + sp * 8;
        dstb[i] = lin * 16;
    }

    // --- fragment LDS byte offsets (K-independent, relative to buf base) ---
    // kk0 logical slot = lq; kk1 = lq^4; phys = logical ^ (row&7)
    int byteA[8][2], byteB[4][2];
    #pragma unroll
    for (int f = 0; f < 8; ++f) {
        int ra = wm * 128 + f * 16 + la;
        byteA[f][0] = ra * 128 + ((lq       ^ (ra & 7)) * 16);
        byteA[f][1] = ra * 128 + (((lq ^ 4) ^ (ra & 7)) * 16);
    }
    #pragma unroll
    for (int n = 0; n < 4; ++n) {
        int rb = wn * 64 + n * 16 + la;
        byteB[n][0] = 32768 + rb * 128 + ((lq       ^ (rb & 7)) * 16);
        byteB[n][1] = 32768 + rb * 128 + (((lq ^ 4) ^ (rb & 7)) * 16);
    }

    f32x4 acc[8][4] = {};

#define STAGE(t1) do { \
    char* db_ = lds + (((t1) & 1) * LBUF); \
    const size_t kof_ = (size_t)(t1) * 64; \
    _Pragma("unroll") \
    for (int i_ = 0; i_ < 4; ++i_) { \
        __builtin_amdgcn_global_load_lds( \
            (const AS1 void*)(qh + aoff[i_] + kof_), \
            (AS3 void*)(db_ + dstb[i_]), 16, 0, 0); \
        __builtin_amdgcn_global_load_lds( \
            (const AS1 void*)(kh + boff[i_] + kof_), \
            (AS3 void*)(db_ + 32768 + dstb[i_]), 16, 0, 0); \
    } } while (0)

    // ---- prologue: stage tile 0 ----
    STAGE(0);
    asm volatile("s_waitcnt vmcnt(0)" ::: "memory");
    __builtin_amdgcn_s_barrier();

    #pragma unroll 1
    for (int t = 0; t < NT; ++t) {
        const char* bufb = lds + (t & 1) * LBUF;

        if (t < NT - 1) STAGE(t + 1);     // 8 loads, full-tile flight

        // B fragments: live across both phases
        bf16x8 bF[4][2];
        #pragma unroll
        for (int n = 0; n < 4; ++n) {
            bF[n][0] = *(const bf16x8*)(bufb + byteB[n][0]);
            bF[n][1] = *(const bf16x8*)(bufb + byteB[n][1]);
        }

        // ---- phase 0: M-frags 0..3 ----
        {
            bf16x8 aF[4][2];
            #pragma unroll
            for (int f = 0; f < 4; ++f) {
                aF[f][0] = *(const bf16x8*)(bufb + byteA[f][0]);
                aF[f][1] = *(const bf16x8*)(bufb + byteA[f][1]);
            }
            __builtin_amdgcn_s_setprio(1);
            #pragma unroll
            for (int f = 0; f < 4; ++f)
                #pragma unroll
                for (int n = 0; n < 4; ++n) {
                    acc[f][n] = __builtin_amdgcn_mfma_f32_16x16x32_bf16(aF[f][0], bF[n][0], acc[f][n], 0, 0, 0);
                    acc[f][n] = __builtin_amdgcn_mfma_f32_16x16x32_bf16(aF[f][1], bF[n][1], acc[f][n], 0, 0, 0);
                }
            __builtin_amdgcn_s_setprio(0);
        }
        __builtin_amdgcn_s_barrier();     // pacing

        // ---- phase 1: M-frags 4..7 ----
        {
            bf16x8 aF[4][2];
            #pragma unroll
            for (int f = 0; f < 4; ++f) {
                aF[f][0] = *(const bf16x8*)(bufb + byteA[f + 4][0]);
                aF[f][1] = *(const bf16x8*)(bufb + byteA[f + 4][1]);
            }
            __builtin_amdgcn_s_setprio(1);
            #pragma unroll
            for (int f = 0; f < 4; ++f)
                #pragma unroll
                for (int n = 0; n < 4; ++n) {
                    acc[f + 4][n] = __builtin_amdgcn_mfma_f32_16x16x32_bf16(aF[f][0], bF[n][0], acc[f + 4][n], 0, 0, 0);
                    acc[f + 4][n] = __builtin_amdgcn_mfma_f32_16x16x32_bf16(aF[f][1], bF[n][1], acc[f + 4][n], 0, 0, 0);
                }
            __builtin_amdgcn_s_setprio(0);
        }
        __syncthreads();                  // tile boundary: drains vmcnt+lgkm
    }
#undef STAGE

    // --- epilogue: e = exp((cos-1)/T); row/col partial sums; atomics ---
    #pragma unroll
    for (int f = 0; f < 8; ++f)
        #pragma unroll
        for (int n = 0; n < 4; ++n)
            #pragma unroll
            for (int r = 0; r < 4; ++r)
                acc[f][n][r] = __expf((acc[f][n][r] - 1.0f) * INV_T);

    // rows: global row = bi*256 + wm*128 + f*16 + lq*4 + r; reduce over la
    #pragma unroll
    for (int f = 0; f < 8; ++f)
        #pragma unroll
        for (int r = 0; r < 4; ++r) {
            float v = acc[f][0][r] + acc[f][1][r] + acc[f][2][r] + acc[f][3][r];
            v += __shfl_xor(v, 1, 64);
            v += __shfl_xor(v, 2, 64);
            v += __shfl_xor(v, 4, 64);
            v += __shfl_xor(v, 8, 64);
            if (la == 0)
                atomicAdd(&rowsum[bi * 256 + wm * 128 + f * 16 + lq * 4 + r], v);
        }

    // cols: global col = bj*256 + wn*64 + n*16 + la; reduce over lq
    #pragma unroll
    for (int n = 0; n < 4; ++n) {
        float v = 0.f;
        #pragma unroll
        for (int f = 0; f < 8; ++f)
            #pragma unroll
            for (int r = 0; r < 4; ++r)
                v += acc[f][n][r];
        v += __shfl_xor(v, 16, 64);
        v += __shfl_xor(v, 32, 64);
        if (lq == 0)
            atomicAdd(&colsum[bj * 256 + wn * 64 + n * 16 + la], v);
    }
}

// ===========================================================================
// Kernel 3: out += sum(0.5*(log rs + log cs) - diag)/N  (out pre-seeded INV_T)
// ===========================================================================
__global__ __launch_bounds__(1024)
void final_kernel(const float* __restrict__ rowsum, const float* __restrict__ colsum,
                  const float* __restrict__ diag, float* __restrict__ out) {
    const int tid = threadIdx.x;
    const int i = blockIdx.x * 1024 + tid;
    float p = 0.5f * (logf(rowsum[i]) + logf(colsum[i])) - diag[i];
    #pragma unroll
    for (int m = 1; m < 64; m <<= 1) p += __shfl_xor(p, m, 64);
    __shared__ float red[16];
    const int wid = tid >> 6, lane = tid & 63;
    if (lane == 0) red[wid] = p;
    __syncthreads();
    if (tid == 0) {
        float t = 0.f;
        #pragma unroll
        for (int w = 0; w < 16; ++w) t += red[w];
        atomicAdd(out, t / (float)N);
    }
}

// ===========================================================================
// FALLBACK PATH (fp32 VALU GEMM, needs only 5*N floats of ws)
// ===========================================================================
#define BT 128
__global__ __launch_bounds__(256)
void norms_diag_kernel(const float* __restrict__ q, const float* __restrict__ k,
                       float* __restrict__ invq, float* __restrict__ invk,
                       float* __restrict__ diag, float* __restrict__ out) {
    const int row = blockIdx.x;
    const int tid = threadIdx.x;
    if (row == 0 && tid == 66) out[0] = INV_T;
    float4 a = *(const float4*)(q + (size_t)row * D + tid * 4);
    float4 b = *(const float4*)(k + (size_t)row * D + tid * 4);
    float sqq = a.x*a.x + a.y*a.y + a.z*a.z + a.w*a.w;
    float skk = b.x*b.x + b.y*b.y + b.z*b.z + b.w*b.w;
    float sqk = a.x*b.x + a.y*b.y + a.z*b.z + a.w*b.w;
    #pragma unroll
    for (int m = 1; m < 64; m <<= 1) {
        sqq += __shfl_xor(sqq, m, 64);
        skk += __shfl_xor(skk, m, 64);
        sqk += __shfl_xor(sqk, m, 64);
    }
    __shared__ float red[3][4];
    const int wid = tid >> 6, lane = tid & 63;
    if (lane == 0) { red[0][wid] = sqq; red[1][wid] = skk; red[2][wid] = sqk; }
    __syncthreads();
    if (tid == 0) {
        float s0 = red[0][0] + red[0][1] + red[0][2] + red[0][3];
        float s1 = red[1][0] + red[1][1] + red[1][2] + red[1][3];
        float s2 = red[2][0] + red[2][1] + red[2][2] + red[2][3];
        float iq = 1.0f / fmaxf(sqrtf(s0), 1e-12f);
        float ik = 1.0f / fmaxf(sqrtf(s1), 1e-12f);
        invq[row] = iq; invk[row] = ik;
        diag[row] = s2 * iq * ik * INV_T;
    }
}

#define KBF 16
#define LDTF 132
__global__ __launch_bounds__(256)
void gemm_lse_kernel(const float* __restrict__ q, const float* __restrict__ k,
                     const float* __restrict__ invq, const float* __restrict__ invk,
                     float* __restrict__ rowsum, float* __restrict__ colsum) {
    __shared__ float As[KBF * LDTF];
    __shared__ float Bs[KBF * LDTF];
    const int tid = threadIdx.x;
    const int tx = tid & 15;
    const int ty = tid >> 4;
    const int bi = blockIdx.y;
    const int bj = blockIdx.x;
    const float* qb = q + (size_t)(bi * BT) * D;
    const float* kb = k + (size_t)(bj * BT) * D;
    float acc[8][8] = {};
    for (int k0 = 0; k0 < D; k0 += KBF) {
        #pragma unroll
        for (int i = 0; i < 2; ++i) {
            int idx  = tid + i * 256;
            int row  = idx >> 2;
            int kc4  = idx & 3;
            float4 av = *(const float4*)(qb + (size_t)row * D + k0 + kc4 * 4);
            float4 bv = *(const float4*)(kb + (size_t)row * D + k0 + kc4 * 4);
            int base = (kc4 * 4) * LDTF + row;
            As[base] = av.x; As[base + LDTF] = av.y; As[base + 2*LDTF] = av.z; As[base + 3*LDTF] = av.w;
            Bs[base] = bv.x; Bs[base + LDTF] = bv.y; Bs[base + 2*LDTF] = bv.z; Bs[base + 3*LDTF] = bv.w;
        }
        __syncthreads();
        #pragma unroll
        for (int kk = 0; kk < KBF; ++kk) {
            const float* ap = &As[kk * LDTF + ty * 8];
            const float* bp = &Bs[kk * LDTF + tx * 8];
            float4 a0 = *(const float4*)(ap);
            float4 a1 = *(const float4*)(ap + 4);
            float4 b0 = *(const float4*)(bp);
            float4 b1 = *(const float4*)(bp + 4);
            float ar[8] = {a0.x, a0.y, a0.z, a0.w, a1.x, a1.y, a1.z, a1.w};
            float br[8] = {b0.x, b0.y, b0.z, b0.w, b1.x, b1.y, b1.z, b1.w};
            #pragma unroll
            for (int r = 0; r < 8; ++r)
                #pragma unroll
                for (int c = 0; c < 8; ++c)
                    acc[r][c] += ar[r] * br[c];
        }
        __syncthreads();
    }
    float iqr[8], ikc[8];
    #pragma unroll
    for (int r = 0; r < 8; ++r) iqr[r] = invq[bi * BT + ty * 8 + r] * INV_T;
    #pragma unroll
    for (int c = 0; c < 8; ++c) ikc[c] = invk[bj * BT + tx * 8 + c];
    float rowpart[8] = {};
    float colpart[8] = {};
    #pragma unroll
    for (int r = 0; r < 8; ++r)
        #pragma unroll
        for (int c = 0; c < 8; ++c) {
            float e = __expf(acc[r][c] * iqr[r] * ikc[c] - INV_T);
            rowpart[r] += e; colpart[c] += e;
        }
    #pragma unroll
    for (int r = 0; r < 8; ++r) {
        float v = rowpart[r];
        v += __shfl_xor(v, 1, 64); v += __shfl_xor(v, 2, 64);
        v += __shfl_xor(v, 4, 64); v += __shfl_xor(v, 8, 64);
        if (tx == 0) atomicAdd(&rowsum[bi * BT + ty * 8 + r], v);
    }
    __syncthreads();
    float* colbuf = As;
    #pragma unroll
    for (int c = 0; c < 8; ++c) colbuf[ty * 128 + tx * 8 + c] = colpart[c];
    __syncthreads();
    if (tid < 128) {
        float s = 0.f;
        #pragma unroll
        for (int t2 = 0; t2 < 16; ++t2) s += colbuf[t2 * 128 + tid];
        atomicAdd(&colsum[bj * BT + tid], s);
    }
}

// ===========================================================================
extern "C" void kernel_launch(void* const* d_in, const int* in_sizes, int n_in,
                              void* d_out, int out_size, void* d_ws, size_t ws_size,
                              hipStream_t stream) {
    const float* q = (const float*)d_in[0];
    const float* k = (const float*)d_in[1];

    const size_t planeBytes = 2ull * N * D * sizeof(ushortT);   // 32 MB (qh+kh)
    const size_t needFast   = planeBytes + 3ull * N * sizeof(float);

    if (ws_size >= needFast) {
        ushortT* qh = (ushortT*)d_ws;
        ushortT* kh = qh + (size_t)N * D;
        float* tail  = (float*)((char*)d_ws + planeBytes);
        float* rowsum = tail;
        float* colsum = tail + N;
        float* diag   = tail + 2 * N;

        normalize_bf16_kernel<<<N, 256, 0, stream>>>(q, k, qh, kh, diag,
                                                     rowsum, colsum, (float*)d_out);
        mfma256_lse_kernel<<<(N / 256) * (N / 256), 512, 0, stream>>>(qh, kh, rowsum, colsum);
        final_kernel<<<N / 1024, 1024, 0, stream>>>(rowsum, colsum, diag, (float*)d_out);
    } else {
        float* ws     = (float*)d_ws;
        float* invq   = ws;
        float* invk   = ws + N;
        float* rowsum = ws + 2 * N;
        float* colsum = ws + 3 * N;
        float* diag   = ws + 4 * N;
        hipMemsetAsync(rowsum, 0, 2ull * N * sizeof(float), stream);
        norms_diag_kernel<<<N, 256, 0, stream>>>(q, k, invq, invk, diag, (float*)d_out);
        gemm_lse_kernel<<<dim3(N / BT, N / BT), 256, 0, stream>>>(q, k, invq, invk, rowsum, colsum);
        final_kernel<<<N / 1024, 1024, 0, stream>>>(rowsum, colsum, diag, (float*)d_out);
    }
}